// Round 18
// baseline (97.557 us; speedup 1.0000x reference)
//
#include <hip/hip_runtime.h>
#include <hip/hip_bf16.h>
#include <math.h>

#define NSEQ 26
#define NSUP 25
#define LSEQ 46
#define DJ 90
#define H1 180
#define DIN 256
#define TT 1035
#define NKT 34       // key tiles incl. one zero pad tile (34*32 = 1088)
#define DOUT 128
#define WAY 5
#define SHOT 5
#define NPB 130      // proto/logits blocks per class: ceil(33120/256)
#define PROWS 8      // rows per featproj block (150*8 = 1200 >= 1196, guarded)
#define SQRT_SCALE 0.29730177875068026f   // (1/sqrt(128))^0.5 folded into K (Q and K both)

typedef __attribute__((ext_vector_type(8))) short short8;
typedef __attribute__((ext_vector_type(4))) float f32x4;

__device__ __forceinline__ ushort f2bf(float x) {
    __hip_bfloat16 h = __float2bfloat16(x);
    return *reinterpret_cast<ushort*>(&h);
}

// ---------------- kernel 1: fused MLP + PE + K/V half-projections ----------------
// Grid (150, 2): block.y picks kw (0) or vw (1); 8 rows per block. This keeps
// ~300 blocks resident (r13 lesson: don't trade TLP for reuse) while cutting
// total weight traffic 231 -> 153 MB and halving the per-block projection
// k-loop (one W matrix instead of two). MLP layers run redundantly in both
// y-halves (cheap) to keep the block self-contained.
__global__ __launch_bounds__(256) void featproj_kernel(
        const float* __restrict__ ss, const float* __restrict__ qsk,
        const float* __restrict__ w1, const float* __restrict__ b1,
        const float* __restrict__ w2, const float* __restrict__ b2,
        const float* __restrict__ kw, const float* __restrict__ vw,
        float* __restrict__ kp1, float* __restrict__ kp2,
        float* __restrict__ vp1, float* __restrict__ vp2) {
    __shared__ float xs[PROWS][DJ];
    __shared__ float hs[PROWS][H1];
    __shared__ float fs[PROWS][DIN];
    int r0 = blockIdx.x * PROWS;
    int tid = threadIdx.x;

    for (int idx = tid; idx < PROWS * DJ; idx += 256) {
        int rr = idx / DJ, e = idx % DJ;
        int r = r0 + rr;
        float v = 0.f;
        if (r < NSEQ * LSEQ) {
            int seq = r / LSEQ, l = r % LSEQ;
            const float* x = (seq < NSUP) ? (ss + (size_t)(seq * LSEQ + l) * DJ)
                                          : (qsk + (size_t)l * DJ);
            v = x[e];
        }
        xs[rr][e] = v;
    }
    __syncthreads();

    if (tid < H1) {   // layer 1: w1 column read once per k, 8 rows amortize
        float acc[PROWS];
        #pragma unroll
        for (int rr = 0; rr < PROWS; ++rr) acc[rr] = b1[tid];
        for (int k = 0; k < DJ; ++k) {
            float wv = w1[k * H1 + tid];
            #pragma unroll
            for (int rr = 0; rr < PROWS; ++rr) acc[rr] += xs[rr][k] * wv;
        }
        #pragma unroll
        for (int rr = 0; rr < PROWS; ++rr) hs[rr][tid] = fmaxf(acc[rr], 0.f);
    }
    __syncthreads();

    {   // layer 2 + relu + positional encoding
        float acc[PROWS];
        #pragma unroll
        for (int rr = 0; rr < PROWS; ++rr) acc[rr] = b2[tid];
        for (int k = 0; k < H1; ++k) {
            float wv = w2[k * DIN + tid];
            #pragma unroll
            for (int rr = 0; rr < PROWS; ++rr) acc[rr] += hs[rr][k] * wv;
        }
        int p2 = tid & ~1;
        float freq = expf((float)p2 * (-9.210340371976184f / 256.0f));
        #pragma unroll
        for (int rr = 0; rr < PROWS; ++rr) {
            int l = (r0 + rr) % LSEQ;
            float ang = (float)l * freq;
            fs[rr][tid] = fmaxf(acc[rr], 0.f) + ((tid & 1) ? cosf(ang) : sinf(ang)) * 0.1f;
        }
    }
    __syncthreads();

    // projection: this block's W only; h = tid>>7 picks half 1 or 2
    int d = tid & 127, h = tid >> 7;
    const float* W = blockIdx.y ? vw : kw;
    float acc[PROWS];
    #pragma unroll
    for (int rr = 0; rr < PROWS; ++rr) acc[rr] = 0.f;
    for (int k = 0; k < DIN; ++k) {
        float wv = W[(size_t)(k + h * DIN) * DOUT + d];
        #pragma unroll
        for (int rr = 0; rr < PROWS; ++rr) acc[rr] += fs[rr][k] * wv;
    }
    float* dst = blockIdx.y ? (h ? vp2 : vp1) : (h ? kp2 : kp1);
    #pragma unroll
    for (int rr = 0; rr < PROWS; ++rr) {
        int r = r0 + rr;
        if (r < NSEQ * LSEQ) dst[(size_t)r * DOUT + d] = acc[rr];
    }
}

// ---------------- kernel 2: tuple gather + bias + LayerNorm ----------------
// Block per (seq, key-tile); kt == 33 is the zero pad tile. K/Q fragment
// stores are 16B per lane. V^T fragments go through a padded LDS tile and
// are emitted as COALESCED 16B chunks (64 lanes -> 1KB contiguous).
__global__ __launch_bounds__(256) void kv_kernel(
        const float* __restrict__ kp1, const float* __restrict__ kp2,
        const float* __restrict__ vp1, const float* __restrict__ vp2,
        const float* __restrict__ kb, const float* __restrict__ vb,
        const float* __restrict__ lg, const float* __restrict__ lb,
        ushort* __restrict__ Qbf, ushort* __restrict__ Kbf2,
        ushort* __restrict__ Vbf2, float* __restrict__ Vq) {
    __shared__ float Vt[32][129];
    int s = blockIdx.x / NKT, kt = blockIdx.x % NKT;
    int tid = threadIdx.x, wid = tid >> 6, lane = tid & 63;
    int lgrp = lane >> 4, dl = lane & 15;
    int d0 = dl * 8;
    int kc = d0 >> 5, gk = (d0 >> 3) & 3;

    #pragma unroll
    for (int pp = 0; pp < 2; ++pp) {
        int jq = pp * 16 + wid * 4 + lgrp;      // tuple within tile, 0..31
        int t = kt * 32 + jq;
        bool valid = t < TT;
        float kv8[8], vv8[8];
        #pragma unroll
        for (int e = 0; e < 8; ++e) { kv8[e] = 0.f; vv8[e] = 0.f; }
        if (valid) {
            int i = (int)((91.0f - sqrtf((float)(8281 - 8 * t))) * 0.5f);
            while (i > 0 && t < i * (91 - i) / 2) --i;
            while (i < 44 && t >= (i + 1) * (90 - i) / 2) ++i;
            int j = i + 1 + (t - i * (91 - i) / 2);
            const float* ki = kp1 + (size_t)(s * LSEQ + i) * DOUT + d0;
            const float* kj = kp2 + (size_t)(s * LSEQ + j) * DOUT + d0;
            const float* vi = vp1 + (size_t)(s * LSEQ + i) * DOUT + d0;
            const float* vj = vp2 + (size_t)(s * LSEQ + j) * DOUT + d0;
            #pragma unroll
            for (int e = 0; e < 8; ++e) {
                kv8[e] = ki[e] + kj[e] + kb[d0 + e];
                vv8[e] = vi[e] + vj[e] + vb[d0 + e];
            }
        }
        float sum = 0.f, sq = 0.f;
        #pragma unroll
        for (int e = 0; e < 8; ++e) { sum += kv8[e]; sq += kv8[e] * kv8[e]; }
        sum += __shfl_xor(sum, 1); sq += __shfl_xor(sq, 1);
        sum += __shfl_xor(sum, 2); sq += __shfl_xor(sq, 2);
        sum += __shfl_xor(sum, 4); sq += __shfl_xor(sq, 4);
        sum += __shfl_xor(sum, 8); sq += __shfl_xor(sq, 8);
        float m = sum * (1.f / DOUT);
        float var = sq * (1.f / DOUT) - m * m;
        float rs = rsqrtf(var + 1e-5f);
        short8 kn8;
        #pragma unroll
        for (int e = 0; e < 8; ++e) {
            float kn = valid ? ((kv8[e] - m) * rs * lg[d0 + e] + lb[d0 + e]) * SQRT_SCALE : 0.f;
            kn8[e] = (short)f2bf(kn);
        }
        if (s < NSUP) {
            int pos = (jq & 4) ? (16 + ((jq >> 3) << 2) + (jq & 3))
                               : (((jq >> 3) << 2) + (jq & 3));
            ushort* Ktile = Kbf2 + ((size_t)s * NKT + kt) * 4096;
            *(short8*)(Ktile + (size_t)((kc * 2 + (pos >> 4)) * 64 + gk * 16 + (pos & 15)) * 8) = kn8;
            #pragma unroll
            for (int e = 0; e < 8; ++e) Vt[jq][d0 + e] = vv8[e];   // valid-masked zeros
        } else {
            int qt = t >> 4, r16q = t & 15;
            *(short8*)(Qbf + (size_t)qt * 2048 + (size_t)(kc * 64 + gk * 16 + r16q) * 8) = kn8;
            if (valid) {
                float* vq = Vq + (size_t)t * DOUT + d0;
                #pragma unroll
                for (int e = 0; e < 8; ++e) vq[e] = vv8[e];
            }
        }
    }
    __syncthreads();
    if (s < NSUP) {
        ushort* Vtile = Vbf2 + ((size_t)s * NKT + kt) * 4096;
        #pragma unroll
        for (int c = tid; c < 512; c += 256) {
            int r16v = c & 15, gv = (c >> 4) & 3, db = c >> 6;
            short8 pk;
            #pragma unroll
            for (int ev = 0; ev < 8; ++ev)
                pk[ev] = (short)f2bf(Vt[gv * 8 + ev][db * 16 + r16v]);
            *(short8*)(Vtile + (size_t)c * 8) = pk;    // coalesced: wave = 1KB run
        }
    }
}

// ---------------- kernel 3: MFMA flash attention, KVBLK=64 chunks ----------------
__global__ __launch_bounds__(256) void attn_mfma_kernel(
        const ushort* __restrict__ Qbf, const ushort* __restrict__ Kbf2,
        const ushort* __restrict__ Vbf2, float* __restrict__ Obuf) {
    __shared__ __align__(16) ushort Kl[2][8192];
    __shared__ __align__(16) ushort Vl[2][8192];

    // bijective XCD-chunk swizzle (nwg=425)
    const int nwg = 17 * NSUP;
    int orig = blockIdx.x;
    int cq = nwg >> 3, cr = nwg & 7;           // 53, 1
    int xcd = orig & 7, sub = orig >> 3;
    int wg = (xcd < cr ? xcd * (cq + 1) : cr * (cq + 1) + (xcd - cr) * cq) + sub;
    int p = wg / 17;

    int tid = threadIdx.x, wid = tid >> 6, lane = tid & 63;
    int g = lane >> 4, r16 = lane & 15;
    int qt = (wg % 17) * 4 + wid;              // 0..67 (66,67 masked)

    const short8 z8 = (short8){0, 0, 0, 0, 0, 0, 0, 0};
    short8 qf[4];
    {
        const ushort* Qb = Qbf + (size_t)qt * 2048;
        bool ok = qt < 66;
        #pragma unroll
        for (int kc = 0; kc < 4; ++kc)
            qf[kc] = ok ? *(const short8*)(Qb + (kc * 64 + lane) * 8) : z8;
    }

    // staging split: wave0 K[0:8KB), wave1 K[8KB:16KB), wave2/3 same for V
    const ushort* gsrc = ((wid < 2) ? Kbf2 : Vbf2) + (size_t)p * NKT * 4096 + (size_t)(wid & 1) * 4096;
    ushort* l0 = ((wid < 2) ? &Kl[0][0] : &Vl[0][0]) + (wid & 1) * 4096;
    ushort* l1 = ((wid < 2) ? &Kl[1][0] : &Vl[1][0]) + (wid & 1) * 4096;

    f32x4 o[8];
    #pragma unroll
    for (int i = 0; i < 8; ++i) o[i] = (f32x4){0.f, 0.f, 0.f, 0.f};
    float lacc = 0.f;

    #pragma unroll
    for (int c = 0; c < 8; ++c)
        __builtin_amdgcn_global_load_lds(
            (const __attribute__((address_space(1))) void*)(gsrc + c * 512 + lane * 8),
            (__attribute__((address_space(3))) void*)(l0 + c * 512), 16, 0, 0);
    __syncthreads();

    for (int cc = 0; cc < 17; ++cc) {
        const ushort* Kc = &Kl[cc & 1][0];
        const ushort* Vc = &Vl[cc & 1][0];
        if (cc + 1 < 17) {   // DMA next chunk into the other buffer
            const ushort* src = gsrc + (size_t)(cc + 1) * 8192;
            ushort* dst = ((cc + 1) & 1) ? l1 : l0;
            #pragma unroll
            for (int c = 0; c < 8; ++c)
                __builtin_amdgcn_global_load_lds(
                    (const __attribute__((address_space(1))) void*)(src + c * 512 + lane * 8),
                    (__attribute__((address_space(3))) void*)(dst + c * 512), 16, 0, 0);
        }
        #pragma unroll
        for (int st = 0; st < 2; ++st) {
            const ushort* Kb = Kc + st * 4096;
            const ushort* Vb = Vc + st * 4096;
            int k0 = cc * 64 + st * 32;
            f32x4 s0 = (f32x4){0.f, 0.f, 0.f, 0.f}, s1 = s0;
            __builtin_amdgcn_s_setprio(1);
            #pragma unroll
            for (int kc = 0; kc < 4; ++kc) {
                short8 kf0 = *(const short8*)(Kb + ((kc * 2 + 0) * 64 + lane) * 8);
                short8 kf1 = *(const short8*)(Kb + ((kc * 2 + 1) * 64 + lane) * 8);
                s0 = __builtin_amdgcn_mfma_f32_16x16x32_bf16(kf0, qf[kc], s0, 0, 0, 0);
                s1 = __builtin_amdgcn_mfma_f32_16x16x32_bf16(kf1, qf[kc], s1, 0, 0, 0);
            }
            __builtin_amdgcn_s_setprio(0);
            float a[8];
            if (k0 + 32 > TT) {   // final tiles incl. zero pad tile
                #pragma unroll
                for (int r = 0; r < 4; ++r) {
                    a[r]     = (k0 + 8 * g + r < TT)     ? __expf(s0[r]) : 0.f;
                    a[4 + r] = (k0 + 8 * g + 4 + r < TT) ? __expf(s1[r]) : 0.f;
                }
            } else {
                #pragma unroll
                for (int r = 0; r < 4; ++r) { a[r] = __expf(s0[r]); a[4 + r] = __expf(s1[r]); }
            }
            lacc += ((a[0] + a[1]) + (a[2] + a[3])) + ((a[4] + a[5]) + (a[6] + a[7]));
            short8 pa;
            #pragma unroll
            for (int e = 0; e < 8; ++e) pa[e] = (short)f2bf(a[e]);
            __builtin_amdgcn_s_setprio(1);
            #pragma unroll
            for (int db = 0; db < 8; ++db) {
                short8 vf = *(const short8*)(Vb + (db * 64 + lane) * 8);
                o[db] = __builtin_amdgcn_mfma_f32_16x16x32_bf16(vf, pa, o[db], 0, 0, 0);
            }
            __builtin_amdgcn_s_setprio(0);
        }
        __syncthreads();   // drains vmcnt (next-chunk DMA landed) + WAR on buf
    }

    lacc += __shfl_xor(lacc, 16);
    lacc += __shfl_xor(lacc, 32);
    float invL = 1.f / lacc;
    int qrow = qt * 16 + r16;
    if (qrow < TT) {
        float* po = Obuf + ((size_t)p * TT + qrow) * DOUT;
        #pragma unroll
        for (int db = 0; db < 8; ++db) {
            float4 w4 = make_float4(o[db][0] * invL, o[db][1] * invL,
                                    o[db][2] * invL, o[db][3] * invL);
            *(float4*)&po[db * 16 + g * 4] = w4;
        }
    }
}

// ---------------- kernel 4: fused proto (shot mean) + logits partials ----------------
__global__ __launch_bounds__(256) void proto_logits_kernel(
        const float* __restrict__ Obuf, const float* __restrict__ Vq,
        float* __restrict__ proto, float* __restrict__ partial) {
    int c = blockIdx.y, tid = threadIdx.x;
    int i = blockIdx.x * 256 + tid;     // float4 index within class
    const int n4 = TT * DOUT / 4;       // 33120
    float sum = 0.f;
    if (i < n4) {
        float4 acc = make_float4(0.f, 0.f, 0.f, 0.f);
        #pragma unroll
        for (int s = 0; s < SHOT; ++s) {
            const float4* O = (const float4*)(Obuf + (size_t)(c * SHOT + s) * TT * DOUT);
            float4 a0 = O[i];
            acc.x += a0.x; acc.y += a0.y; acc.z += a0.z; acc.w += a0.w;
        }
        acc.x *= 0.2f; acc.y *= 0.2f; acc.z *= 0.2f; acc.w *= 0.2f;
        ((float4*)(proto + (size_t)c * TT * DOUT))[i] = acc;
        float4 qv4 = ((const float4*)Vq)[i];
        float dx = qv4.x - acc.x, dy = qv4.y - acc.y;
        float dz = qv4.z - acc.z, dw = qv4.w - acc.w;
        sum = dx * dx + dy * dy + dz * dz + dw * dw;
    }
    for (int off = 32; off >= 1; off >>= 1) sum += __shfl_down(sum, off);
    __shared__ float red[4];
    int w = tid >> 6, lane = tid & 63;
    if (lane == 0) red[w] = sum;
    __syncthreads();
    if (tid == 0) partial[c * NPB + blockIdx.x] = red[0] + red[1] + red[2] + red[3];
}

// ---------------- kernel 5: fused logits finalize + argmax + is_true ----------------
__global__ __launch_bounds__(256) void istrue_kernel(
        const float* __restrict__ Vq, const float* __restrict__ proto,
        const float* __restrict__ partial, float* out) {
    __shared__ float lgv[WAY];
    int tid = threadIdx.x, wv = tid >> 6, lane = tid & 63;
    for (int c = wv; c < WAY; c += 4) {
        float s = 0.f;
        for (int b = lane; b < NPB; b += 64) s += partial[c * NPB + b];
        for (int off = 32; off >= 1; off >>= 1) s += __shfl_down(s, off);
        if (lane == 0) lgv[c] = -s / (float)TT;
    }
    __syncthreads();
    float l0 = lgv[0];
    int best = 0;
    #pragma unroll
    for (int cc = 1; cc < WAY; ++cc) {
        float lc = lgv[cc];
        if (lc > l0) { l0 = lc; best = cc; }
    }
    if (blockIdx.x == 0 && tid < WAY) out[tid] = lgv[tid];
    int idx = blockIdx.x * 256 + tid;
    if (idx < TT * DOUT)
        out[5 + idx] = expf(Vq[idx] - proto[(size_t)best * TT * DOUT + idx]);
}

extern "C" void kernel_launch(void* const* d_in, const int* in_sizes, int n_in,
                              void* d_out, int out_size, void* d_ws, size_t ws_size,
                              hipStream_t stream) {
    const float* ss  = (const float*)d_in[0];
    const float* qsk = (const float*)d_in[1];
    // d_in[2] = ss_labels (sorted balanced; reduces to a reshape)
    const float* w1 = (const float*)d_in[3];
    const float* b1 = (const float*)d_in[4];
    const float* w2 = (const float*)d_in[5];
    const float* b2 = (const float*)d_in[6];
    const float* kw = (const float*)d_in[7];
    const float* kb = (const float*)d_in[8];
    const float* vw = (const float*)d_in[9];
    const float* vb = (const float*)d_in[10];
    const float* lg = (const float*)d_in[11];
    const float* lb = (const float*)d_in[12];
    float* out = (float*)d_out;

    float* w = (float*)d_ws;
    float* kp1  = w;                                   // 1196*128 f32 each
    float* kp2  = kp1 + 1196 * 128;
    float* vp1  = kp2 + 1196 * 128;
    float* vp2  = vp1 + 1196 * 128;
    float* Vq   = vp2 + 1196 * 128;                    // TT*128 f32 (query V)
    float* Obuf = Vq + (size_t)TT * DOUT;              // 25*TT*128 f32 (normalized)
    float* proto = Obuf + (size_t)NSUP * TT * DOUT;    // 5*TT*128 f32
    float* partial = proto + (size_t)WAY * TT * DOUT;  // WAY*NPB f32
    ushort* Qbf  = (ushort*)(partial + WAY * NPB);     // 72*2048 u16 (frag-order Q)
    ushort* Kbf2 = Qbf + (size_t)72 * 2048;            // 25*34*4096 u16 (incl. pad tile)
    ushort* Vbf2 = Kbf2 + (size_t)NSUP * NKT * 4096;   // 25*34*4096 u16
    // total ~34 MB

    hipLaunchKernelGGL(featproj_kernel, dim3(150, 2), dim3(256), 0, stream,
                       ss, qsk, w1, b1, w2, b2, kw, vw, kp1, kp2, vp1, vp2);
    hipLaunchKernelGGL(kv_kernel, dim3(NSEQ * NKT), dim3(256), 0, stream,
                       kp1, kp2, vp1, vp2, kb, vb, lg, lb, Qbf, Kbf2, Vbf2, Vq);
    hipLaunchKernelGGL(attn_mfma_kernel, dim3(17 * NSUP), dim3(256), 0, stream,
                       Qbf, Kbf2, Vbf2, Obuf);
    hipLaunchKernelGGL(proto_logits_kernel, dim3(NPB, WAY), dim3(256), 0, stream,
                       Obuf, Vq, proto, partial);
    hipLaunchKernelGGL(istrue_kernel, dim3((TT * DOUT + 255) / 256), dim3(256), 0, stream,
                       Vq, proto, partial, out);
}

// Round 19
// 85.191 us; speedup vs baseline: 1.1452x; 1.1452x over previous
//
#include <hip/hip_runtime.h>
#include <hip/hip_bf16.h>
#include <math.h>

#define NSEQ 26
#define NSUP 25
#define LSEQ 46
#define DJ 90
#define H1 180
#define DIN 256
#define TT 1035
#define NKT 34       // key tiles incl. one zero pad tile (34*32 = 1088)
#define DOUT 128
#define WAY 5
#define SHOT 5
#define NPB 130      // proto/logits blocks per class: ceil(33120/256)
#define PROWS 4      // proj rows per block (1196 = 4*299)
#define SQRT_SCALE 0.29730177875068026f   // (1/sqrt(128))^0.5 folded into K (Q and K both)

typedef __attribute__((ext_vector_type(8))) short short8;
typedef __attribute__((ext_vector_type(4))) float f32x4;

__device__ __forceinline__ ushort f2bf(float x) {
    __hip_bfloat16 h = __float2bfloat16(x);
    return *reinterpret_cast<ushort*>(&h);
}

// ---------------- kernel 1: MLP (two relu layers) + positional encoding ----------------
// 1196 blocks (4.7/CU, ~19 waves/CU): enough TLP to hide the serial weight-
// column loads. r18 lesson (3rd confirmation of r13): block count beats
// weight-reuse for this L2-resident working set — latency, not BW, dominates.
__global__ void mlp_pe_kernel(const float* __restrict__ ss, const float* __restrict__ qsk,
                              const float* __restrict__ w1, const float* __restrict__ b1,
                              const float* __restrict__ w2, const float* __restrict__ b2,
                              float* __restrict__ feat) {
    __shared__ float xs[DJ];
    __shared__ float hs[H1];
    int r = blockIdx.x;
    int seq = r / LSEQ, l = r % LSEQ;
    const float* x = (seq < NSUP) ? (ss + (size_t)(seq * LSEQ + l) * DJ)
                                  : (qsk + (size_t)l * DJ);
    int tid = threadIdx.x;
    if (tid < DJ) xs[tid] = x[tid];
    __syncthreads();
    if (tid < H1) {
        float a = b1[tid];
        for (int k = 0; k < DJ; ++k) a += xs[k] * w1[k * H1 + tid];
        hs[tid] = fmaxf(a, 0.f);
    }
    __syncthreads();
    int d = tid;  // 0..255
    float a = b2[d];
    for (int k = 0; k < H1; ++k) a += hs[k] * w2[k * DIN + d];
    a = fmaxf(a, 0.f);
    int p2 = d & ~1;
    float freq = expf((float)p2 * (-9.210340371976184f / 256.0f));
    float ang = (float)l * freq;
    a += ((d & 1) ? cosf(ang) : sinf(ang)) * 0.1f;
    feat[(size_t)r * DIN + d] = a;
}

// ---------------- kernel 2: half projections, grid (299, 4) ----------------
// blockIdx.y picks ONE output panel {kp1,kp2,vp1,vp2}; 4 rows/block, 2 rows
// per thread. Same total weight traffic as a fused block (157 MB) but 4x the
// resident blocks (1196 = 4.7/CU) -> latency hidden by TLP, not reuse.
__global__ __launch_bounds__(256) void proj_kernel(
        const float* __restrict__ feat,
        const float* __restrict__ kw, const float* __restrict__ vw,
        float* __restrict__ kp1, float* __restrict__ kp2,
        float* __restrict__ vp1, float* __restrict__ vp2) {
    __shared__ float fs[PROWS][DIN];
    int r0 = blockIdx.x * PROWS;
    int tid = threadIdx.x;
    int panel = blockIdx.y;              // 0:kp1 1:kp2 2:vp1 3:vp2
    const float* W = ((panel < 2) ? kw : vw) + (size_t)(panel & 1) * DIN * DOUT;
    float* dst = (panel == 0) ? kp1 : (panel == 1) ? kp2 : (panel == 2) ? vp1 : vp2;
    #pragma unroll
    for (int rr = 0; rr < PROWS; ++rr)
        fs[rr][tid] = feat[(size_t)(r0 + rr) * DIN + tid];
    __syncthreads();
    int d = tid & 127, rh = tid >> 7;    // rh=0: rows 0,1; rh=1: rows 2,3
    float a0 = 0.f, a1 = 0.f;
    #pragma unroll 8
    for (int k = 0; k < DIN; ++k) {
        float wv = W[(size_t)k * DOUT + d];
        a0 += fs[rh * 2 + 0][k] * wv;
        a1 += fs[rh * 2 + 1][k] * wv;
    }
    dst[(size_t)(r0 + rh * 2 + 0) * DOUT + d] = a0;
    dst[(size_t)(r0 + rh * 2 + 1) * DOUT + d] = a1;
}

// ---------------- kernel 3: tuple gather + bias + LayerNorm ----------------
// Block per (seq, key-tile); kt == 33 is the zero pad tile. K/Q fragment
// stores are 16B per lane. V^T fragments go through a padded LDS tile and
// are emitted as COALESCED 16B chunks (64 lanes -> 1KB contiguous).
__global__ __launch_bounds__(256) void kv_kernel(
        const float* __restrict__ kp1, const float* __restrict__ kp2,
        const float* __restrict__ vp1, const float* __restrict__ vp2,
        const float* __restrict__ kb, const float* __restrict__ vb,
        const float* __restrict__ lg, const float* __restrict__ lb,
        ushort* __restrict__ Qbf, ushort* __restrict__ Kbf2,
        ushort* __restrict__ Vbf2, float* __restrict__ Vq) {
    __shared__ float Vt[32][129];
    int s = blockIdx.x / NKT, kt = blockIdx.x % NKT;
    int tid = threadIdx.x, wid = tid >> 6, lane = tid & 63;
    int lgrp = lane >> 4, dl = lane & 15;
    int d0 = dl * 8;
    int kc = d0 >> 5, gk = (d0 >> 3) & 3;

    #pragma unroll
    for (int pp = 0; pp < 2; ++pp) {
        int jq = pp * 16 + wid * 4 + lgrp;      // tuple within tile, 0..31
        int t = kt * 32 + jq;
        bool valid = t < TT;
        float kv8[8], vv8[8];
        #pragma unroll
        for (int e = 0; e < 8; ++e) { kv8[e] = 0.f; vv8[e] = 0.f; }
        if (valid) {
            int i = (int)((91.0f - sqrtf((float)(8281 - 8 * t))) * 0.5f);
            while (i > 0 && t < i * (91 - i) / 2) --i;
            while (i < 44 && t >= (i + 1) * (90 - i) / 2) ++i;
            int j = i + 1 + (t - i * (91 - i) / 2);
            const float* ki = kp1 + (size_t)(s * LSEQ + i) * DOUT + d0;
            const float* kj = kp2 + (size_t)(s * LSEQ + j) * DOUT + d0;
            const float* vi = vp1 + (size_t)(s * LSEQ + i) * DOUT + d0;
            const float* vj = vp2 + (size_t)(s * LSEQ + j) * DOUT + d0;
            #pragma unroll
            for (int e = 0; e < 8; ++e) {
                kv8[e] = ki[e] + kj[e] + kb[d0 + e];
                vv8[e] = vi[e] + vj[e] + vb[d0 + e];
            }
        }
        float sum = 0.f, sq = 0.f;
        #pragma unroll
        for (int e = 0; e < 8; ++e) { sum += kv8[e]; sq += kv8[e] * kv8[e]; }
        sum += __shfl_xor(sum, 1); sq += __shfl_xor(sq, 1);
        sum += __shfl_xor(sum, 2); sq += __shfl_xor(sq, 2);
        sum += __shfl_xor(sum, 4); sq += __shfl_xor(sq, 4);
        sum += __shfl_xor(sum, 8); sq += __shfl_xor(sq, 8);
        float m = sum * (1.f / DOUT);
        float var = sq * (1.f / DOUT) - m * m;
        float rs = rsqrtf(var + 1e-5f);
        short8 kn8;
        #pragma unroll
        for (int e = 0; e < 8; ++e) {
            float kn = valid ? ((kv8[e] - m) * rs * lg[d0 + e] + lb[d0 + e]) * SQRT_SCALE : 0.f;
            kn8[e] = (short)f2bf(kn);
        }
        if (s < NSUP) {
            int pos = (jq & 4) ? (16 + ((jq >> 3) << 2) + (jq & 3))
                               : (((jq >> 3) << 2) + (jq & 3));
            ushort* Ktile = Kbf2 + ((size_t)s * NKT + kt) * 4096;
            *(short8*)(Ktile + (size_t)((kc * 2 + (pos >> 4)) * 64 + gk * 16 + (pos & 15)) * 8) = kn8;
            #pragma unroll
            for (int e = 0; e < 8; ++e) Vt[jq][d0 + e] = vv8[e];   // valid-masked zeros
        } else {
            int qt = t >> 4, r16q = t & 15;
            *(short8*)(Qbf + (size_t)qt * 2048 + (size_t)(kc * 64 + gk * 16 + r16q) * 8) = kn8;
            if (valid) {
                float* vq = Vq + (size_t)t * DOUT + d0;
                #pragma unroll
                for (int e = 0; e < 8; ++e) vq[e] = vv8[e];
            }
        }
    }
    __syncthreads();
    if (s < NSUP) {
        ushort* Vtile = Vbf2 + ((size_t)s * NKT + kt) * 4096;
        #pragma unroll
        for (int c = tid; c < 512; c += 256) {
            int r16v = c & 15, gv = (c >> 4) & 3, db = c >> 6;
            short8 pk;
            #pragma unroll
            for (int ev = 0; ev < 8; ++ev)
                pk[ev] = (short)f2bf(Vt[gv * 8 + ev][db * 16 + r16v]);
            *(short8*)(Vtile + (size_t)c * 8) = pk;    // coalesced: wave = 1KB run
        }
    }
}

// ---------------- kernel 4: MFMA flash attention, KVBLK=64 chunks ----------------
__global__ __launch_bounds__(256) void attn_mfma_kernel(
        const ushort* __restrict__ Qbf, const ushort* __restrict__ Kbf2,
        const ushort* __restrict__ Vbf2, float* __restrict__ Obuf) {
    __shared__ __align__(16) ushort Kl[2][8192];
    __shared__ __align__(16) ushort Vl[2][8192];

    // bijective XCD-chunk swizzle (nwg=425)
    const int nwg = 17 * NSUP;
    int orig = blockIdx.x;
    int cq = nwg >> 3, cr = nwg & 7;           // 53, 1
    int xcd = orig & 7, sub = orig >> 3;
    int wg = (xcd < cr ? xcd * (cq + 1) : cr * (cq + 1) + (xcd - cr) * cq) + sub;
    int p = wg / 17;

    int tid = threadIdx.x, wid = tid >> 6, lane = tid & 63;
    int g = lane >> 4, r16 = lane & 15;
    int qt = (wg % 17) * 4 + wid;              // 0..67 (66,67 masked)

    const short8 z8 = (short8){0, 0, 0, 0, 0, 0, 0, 0};
    short8 qf[4];
    {
        const ushort* Qb = Qbf + (size_t)qt * 2048;
        bool ok = qt < 66;
        #pragma unroll
        for (int kc = 0; kc < 4; ++kc)
            qf[kc] = ok ? *(const short8*)(Qb + (kc * 64 + lane) * 8) : z8;
    }

    // staging split: wave0 K[0:8KB), wave1 K[8KB:16KB), wave2/3 same for V
    const ushort* gsrc = ((wid < 2) ? Kbf2 : Vbf2) + (size_t)p * NKT * 4096 + (size_t)(wid & 1) * 4096;
    ushort* l0 = ((wid < 2) ? &Kl[0][0] : &Vl[0][0]) + (wid & 1) * 4096;
    ushort* l1 = ((wid < 2) ? &Kl[1][0] : &Vl[1][0]) + (wid & 1) * 4096;

    f32x4 o[8];
    #pragma unroll
    for (int i = 0; i < 8; ++i) o[i] = (f32x4){0.f, 0.f, 0.f, 0.f};
    float lacc = 0.f;

    #pragma unroll
    for (int c = 0; c < 8; ++c)
        __builtin_amdgcn_global_load_lds(
            (const __attribute__((address_space(1))) void*)(gsrc + c * 512 + lane * 8),
            (__attribute__((address_space(3))) void*)(l0 + c * 512), 16, 0, 0);
    __syncthreads();

    for (int cc = 0; cc < 17; ++cc) {
        const ushort* Kc = &Kl[cc & 1][0];
        const ushort* Vc = &Vl[cc & 1][0];
        if (cc + 1 < 17) {   // DMA next chunk into the other buffer
            const ushort* src = gsrc + (size_t)(cc + 1) * 8192;
            ushort* dst = ((cc + 1) & 1) ? l1 : l0;
            #pragma unroll
            for (int c = 0; c < 8; ++c)
                __builtin_amdgcn_global_load_lds(
                    (const __attribute__((address_space(1))) void*)(src + c * 512 + lane * 8),
                    (__attribute__((address_space(3))) void*)(dst + c * 512), 16, 0, 0);
        }
        #pragma unroll
        for (int st = 0; st < 2; ++st) {
            const ushort* Kb = Kc + st * 4096;
            const ushort* Vb = Vc + st * 4096;
            int k0 = cc * 64 + st * 32;
            f32x4 s0 = (f32x4){0.f, 0.f, 0.f, 0.f}, s1 = s0;
            __builtin_amdgcn_s_setprio(1);
            #pragma unroll
            for (int kc = 0; kc < 4; ++kc) {
                short8 kf0 = *(const short8*)(Kb + ((kc * 2 + 0) * 64 + lane) * 8);
                short8 kf1 = *(const short8*)(Kb + ((kc * 2 + 1) * 64 + lane) * 8);
                s0 = __builtin_amdgcn_mfma_f32_16x16x32_bf16(kf0, qf[kc], s0, 0, 0, 0);
                s1 = __builtin_amdgcn_mfma_f32_16x16x32_bf16(kf1, qf[kc], s1, 0, 0, 0);
            }
            __builtin_amdgcn_s_setprio(0);
            float a[8];
            if (k0 + 32 > TT) {   // final tiles incl. zero pad tile
                #pragma unroll
                for (int r = 0; r < 4; ++r) {
                    a[r]     = (k0 + 8 * g + r < TT)     ? __expf(s0[r]) : 0.f;
                    a[4 + r] = (k0 + 8 * g + 4 + r < TT) ? __expf(s1[r]) : 0.f;
                }
            } else {
                #pragma unroll
                for (int r = 0; r < 4; ++r) { a[r] = __expf(s0[r]); a[4 + r] = __expf(s1[r]); }
            }
            lacc += ((a[0] + a[1]) + (a[2] + a[3])) + ((a[4] + a[5]) + (a[6] + a[7]));
            short8 pa;
            #pragma unroll
            for (int e = 0; e < 8; ++e) pa[e] = (short)f2bf(a[e]);
            __builtin_amdgcn_s_setprio(1);
            #pragma unroll
            for (int db = 0; db < 8; ++db) {
                short8 vf = *(const short8*)(Vb + (db * 64 + lane) * 8);
                o[db] = __builtin_amdgcn_mfma_f32_16x16x32_bf16(vf, pa, o[db], 0, 0, 0);
            }
            __builtin_amdgcn_s_setprio(0);
        }
        __syncthreads();   // drains vmcnt (next-chunk DMA landed) + WAR on buf
    }

    lacc += __shfl_xor(lacc, 16);
    lacc += __shfl_xor(lacc, 32);
    float invL = 1.f / lacc;
    int qrow = qt * 16 + r16;
    if (qrow < TT) {
        float* po = Obuf + ((size_t)p * TT + qrow) * DOUT;
        #pragma unroll
        for (int db = 0; db < 8; ++db) {
            float4 w4 = make_float4(o[db][0] * invL, o[db][1] * invL,
                                    o[db][2] * invL, o[db][3] * invL);
            *(float4*)&po[db * 16 + g * 4] = w4;
        }
    }
}

// ---------------- kernel 5: fused proto (shot mean) + logits partials ----------------
__global__ __launch_bounds__(256) void proto_logits_kernel(
        const float* __restrict__ Obuf, const float* __restrict__ Vq,
        float* __restrict__ proto, float* __restrict__ partial) {
    int c = blockIdx.y, tid = threadIdx.x;
    int i = blockIdx.x * 256 + tid;     // float4 index within class
    const int n4 = TT * DOUT / 4;       // 33120
    float sum = 0.f;
    if (i < n4) {
        float4 acc = make_float4(0.f, 0.f, 0.f, 0.f);
        #pragma unroll
        for (int s = 0; s < SHOT; ++s) {
            const float4* O = (const float4*)(Obuf + (size_t)(c * SHOT + s) * TT * DOUT);
            float4 a0 = O[i];
            acc.x += a0.x; acc.y += a0.y; acc.z += a0.z; acc.w += a0.w;
        }
        acc.x *= 0.2f; acc.y *= 0.2f; acc.z *= 0.2f; acc.w *= 0.2f;
        ((float4*)(proto + (size_t)c * TT * DOUT))[i] = acc;
        float4 qv4 = ((const float4*)Vq)[i];
        float dx = qv4.x - acc.x, dy = qv4.y - acc.y;
        float dz = qv4.z - acc.z, dw = qv4.w - acc.w;
        sum = dx * dx + dy * dy + dz * dz + dw * dw;
    }
    for (int off = 32; off >= 1; off >>= 1) sum += __shfl_down(sum, off);
    __shared__ float red[4];
    int w = tid >> 6, lane = tid & 63;
    if (lane == 0) red[w] = sum;
    __syncthreads();
    if (tid == 0) partial[c * NPB + blockIdx.x] = red[0] + red[1] + red[2] + red[3];
}

// ---------------- kernel 6: fused logits finalize + argmax + is_true ----------------
__global__ __launch_bounds__(256) void istrue_kernel(
        const float* __restrict__ Vq, const float* __restrict__ proto,
        const float* __restrict__ partial, float* out) {
    __shared__ float lgv[WAY];
    int tid = threadIdx.x, wv = tid >> 6, lane = tid & 63;
    for (int c = wv; c < WAY; c += 4) {
        float s = 0.f;
        for (int b = lane; b < NPB; b += 64) s += partial[c * NPB + b];
        for (int off = 32; off >= 1; off >>= 1) s += __shfl_down(s, off);
        if (lane == 0) lgv[c] = -s / (float)TT;
    }
    __syncthreads();
    float l0 = lgv[0];
    int best = 0;
    #pragma unroll
    for (int cc = 1; cc < WAY; ++cc) {
        float lc = lgv[cc];
        if (lc > l0) { l0 = lc; best = cc; }
    }
    if (blockIdx.x == 0 && tid < WAY) out[tid] = lgv[tid];
    int idx = blockIdx.x * 256 + tid;
    if (idx < TT * DOUT)
        out[5 + idx] = expf(Vq[idx] - proto[(size_t)best * TT * DOUT + idx]);
}

extern "C" void kernel_launch(void* const* d_in, const int* in_sizes, int n_in,
                              void* d_out, int out_size, void* d_ws, size_t ws_size,
                              hipStream_t stream) {
    const float* ss  = (const float*)d_in[0];
    const float* qsk = (const float*)d_in[1];
    // d_in[2] = ss_labels (sorted balanced; reduces to a reshape)
    const float* w1 = (const float*)d_in[3];
    const float* b1 = (const float*)d_in[4];
    const float* w2 = (const float*)d_in[5];
    const float* b2 = (const float*)d_in[6];
    const float* kw = (const float*)d_in[7];
    const float* kb = (const float*)d_in[8];
    const float* vw = (const float*)d_in[9];
    const float* vb = (const float*)d_in[10];
    const float* lg = (const float*)d_in[11];
    const float* lb = (const float*)d_in[12];
    float* out = (float*)d_out;

    float* w = (float*)d_ws;
    float* feat = w;                                   // 1196*256 f32
    float* kp1  = feat + 1196 * 256;                   // 1196*128 f32 each
    float* kp2  = kp1 + 1196 * 128;
    float* vp1  = kp2 + 1196 * 128;
    float* vp2  = vp1 + 1196 * 128;
    float* Vq   = vp2 + 1196 * 128;                    // TT*128 f32 (query V)
    float* Obuf = Vq + (size_t)TT * DOUT;              // 25*TT*128 f32 (normalized)
    float* proto = Obuf + (size_t)NSUP * TT * DOUT;    // 5*TT*128 f32
    float* partial = proto + (size_t)WAY * TT * DOUT;  // WAY*NPB f32
    ushort* Qbf  = (ushort*)(partial + WAY * NPB);     // 72*2048 u16 (frag-order Q)
    ushort* Kbf2 = Qbf + (size_t)72 * 2048;            // 25*34*4096 u16 (incl. pad tile)
    ushort* Vbf2 = Kbf2 + (size_t)NSUP * NKT * 4096;   // 25*34*4096 u16
    // total ~35 MB

    hipLaunchKernelGGL(mlp_pe_kernel, dim3(NSEQ * LSEQ), dim3(256), 0, stream,
                       ss, qsk, w1, b1, w2, b2, feat);
    hipLaunchKernelGGL(proj_kernel, dim3(299, 4), dim3(256), 0, stream,
                       feat, kw, vw, kp1, kp2, vp1, vp2);
    hipLaunchKernelGGL(kv_kernel, dim3(NSEQ * NKT), dim3(256), 0, stream,
                       kp1, kp2, vp1, vp2, kb, vb, lg, lb, Qbf, Kbf2, Vbf2, Vq);
    hipLaunchKernelGGL(attn_mfma_kernel, dim3(17 * NSUP), dim3(256), 0, stream,
                       Qbf, Kbf2, Vbf2, Obuf);
    hipLaunchKernelGGL(proto_logits_kernel, dim3(NPB, WAY), dim3(256), 0, stream,
                       Obuf, Vq, proto, partial);
    hipLaunchKernelGGL(istrue_kernel, dim3((TT * DOUT + 255) / 256), dim3(256), 0, stream,
                       Vq, proto, partial, out);
}